// Round 3
// baseline (304.425 us; speedup 1.0000x reference)
//
#include <hip/hip_runtime.h>

#define N_NODES 1536
#define PP 1178880LL   // N*(N-1)/2

// ws layout (bytes):
//   Ap_d : double[N][64]   offset 0        (786432)  = Ap + bp1 (fp64 chain)
//   BpT_d: double[64][N]   offset 786432   (786432)
//   Af_f : float [N][64]   offset 1572864  (393216)  = Af + bf1
//   BfT_f: float [64][N]   offset 1966080  (393216)
// total 2359296 bytes

__global__ __launch_bounds__(64) void k1_encode(
    const float* __restrict__ X,  const float* __restrict__ W1, const float* __restrict__ b1,
    const float* __restrict__ W2, const float* __restrict__ b2,
    const float* __restrict__ Wp1, const float* __restrict__ bp1,
    const float* __restrict__ Wf1, const float* __restrict__ bf1,
    double* __restrict__ Ap_d, double* __restrict__ BpT_d,
    float* __restrict__ Af_f, float* __restrict__ BfT_f)
{
    const int i = blockIdx.x;
    const int t = threadIdx.x;
    __shared__ double sh1[64];
    __shared__ double se[64];

    // stage 1: h1[t] = relu(dot(X[i], W1[t]) + b1[t])   (fp64 accumulate)
    double acc = (double)b1[t];
    const float4* Xv  = (const float4*)(X  + (size_t)i * 128);
    const float4* W1v = (const float4*)(W1 + (size_t)t * 128);
    #pragma unroll
    for (int d = 0; d < 32; ++d) {
        float4 x = Xv[d]; float4 w = W1v[d];
        acc += (double)x.x * (double)w.x + (double)x.y * (double)w.y
             + (double)x.z * (double)w.z + (double)x.w * (double)w.w;
    }
    sh1[t] = acc > 0.0 ? acc : 0.0;
    __syncthreads();

    // stage 2: enc[t] = dot(h1, W2[t]) + b2[t]
    double e = (double)b2[t];
    const float4* W2v = (const float4*)(W2 + (size_t)t * 64);
    #pragma unroll
    for (int d = 0; d < 16; ++d) {
        float4 w = W2v[d];
        e += sh1[d*4+0] * (double)w.x + sh1[d*4+1] * (double)w.y
           + sh1[d*4+2] * (double)w.z + sh1[d*4+3] * (double)w.w;
    }
    __syncthreads();
    se[t] = e;
    __syncthreads();

    // stage 3: four projections of enc row
    double ap = (double)bp1[t], bp = 0.0, af = (double)bf1[t], bf = 0.0;
    const float4* WpA = (const float4*)(Wp1 + (size_t)t * 128);
    const float4* WpB = (const float4*)(Wp1 + (size_t)t * 128 + 64);
    const float4* WfA = (const float4*)(Wf1 + (size_t)t * 128);
    const float4* WfB = (const float4*)(Wf1 + (size_t)t * 128 + 64);
    #pragma unroll
    for (int d = 0; d < 16; ++d) {
        double e0 = se[d*4+0], e1 = se[d*4+1], e2 = se[d*4+2], e3 = se[d*4+3];
        float4 wa = WpA[d], wb = WpB[d], fa = WfA[d], fb = WfB[d];
        ap += e0*(double)wa.x + e1*(double)wa.y + e2*(double)wa.z + e3*(double)wa.w;
        bp += e0*(double)wb.x + e1*(double)wb.y + e2*(double)wb.z + e3*(double)wb.w;
        af += e0*(double)fa.x + e1*(double)fa.y + e2*(double)fa.z + e3*(double)fa.w;
        bf += e0*(double)fb.x + e1*(double)fb.y + e2*(double)fb.z + e3*(double)fb.w;
    }
    Ap_d[(size_t)i * 64 + t]       = ap;
    BpT_d[(size_t)t * N_NODES + i] = bp;
    Af_f[(size_t)i * 64 + t]       = (float)af;
    BfT_f[(size_t)t * N_NODES + i] = (float)bf;
}

__global__ __launch_bounds__(256) void k2_pairs(
    const double* __restrict__ Ap_d, const double* __restrict__ BpT_d,
    const float* __restrict__ Af_f, const float* __restrict__ BfT_f,
    const float* __restrict__ wp2, const float* __restrict__ bp2,
    const float* __restrict__ Wf2, const float* __restrict__ bf2,
    float* __restrict__ out)
{
    const int bj = blockIdx.x, bi = blockIdx.y;
    const int i0 = bi * 16, j0 = bj * 64;
    if (i0 >= j0 + 63) return;                  // tile entirely below diagonal

    __shared__ double sBp[64 * 64];
    __shared__ float  sBf[64 * 64];
    const int tid = threadIdx.x;

    // stage B-side tiles (transposed layout [k][j]), coalesced
    #pragma unroll
    for (int a = 0; a < 8; ++a) {
        int F = tid + a * 256;                  // double2 index 0..2047
        int k = F >> 5, q = F & 31;
        ((double2*)sBp)[F] = *((const double2*)(BpT_d + (size_t)k * N_NODES + j0) + q);
    }
    #pragma unroll
    for (int a = 0; a < 4; ++a) {
        int F = tid + a * 256;                  // float4 index 0..1023
        int k = F >> 4, q = F & 15;
        ((float4*)sBf)[F] = *((const float4*)(BfT_f + (size_t)k * N_NODES + j0) + q);
    }
    __syncthreads();

    const int w = tid >> 6, lane = tid & 63;
    const int j = j0 + lane;
    const double bp2v = (double)bp2[0];

    for (int ii = 0; ii < 4; ++ii) {
        const int i = i0 + w * 4 + ii;
        if (i >= j0 + 63) break;                // no valid j for this (and later) i
        const double* aprow = Ap_d + (size_t)i * 64;
        const float*  afrow = Af_f + (size_t)i * 64;

        double logit = bp2v;
        float feat[32];
        #pragma unroll
        for (int c = 0; c < 32; ++c) feat[c] = bf2[c];

        for (int k0 = 0; k0 < 64; k0 += 8) {
            float g8[8];
            #pragma unroll
            for (int kk = 0; kk < 8; ++kk) {
                const int k = k0 + kk;
                double hb = aprow[k] + sBp[k * 64 + lane];     // s_load + ds_read_b64
                hb = hb > 0.0 ? hb : 0.0;
                logit += hb * (double)wp2[k];                  // wp2 uniform -> sgpr
                float gb = afrow[k] + sBf[k * 64 + lane];
                g8[kk] = fmaxf(gb, 0.f);
            }
            #pragma unroll
            for (int c = 0; c < 32; ++c) {
                const float* wr = Wf2 + c * 64 + k0;           // uniform -> s_load_dwordx8
                #pragma unroll
                for (int kk = 0; kk < 8; ++kk)
                    feat[c] = fmaf(g8[kk], wr[kk], feat[c]);
            }
        }

        if (j > i) {
            const float m = (logit > 0.0) ? 1.0f : 0.0f;       // sigmoid(l)>0.5 <=> l>0
            const long long p = (long long)i * (N_NODES - 1)
                              - ((long long)i * (i - 1)) / 2 + (j - i - 1);
            ((float2*)out)[p]              = make_float2((float)i, (float)j);
            ((float2*)(out + 2 * PP))[p]   = make_float2((float)j, (float)i);
            ((float2*)(out + 4 * PP))[p]   = make_float2(m, m);
            float* ab = out + 6 * PP + (p << 6);
            #pragma unroll
            for (int c4 = 0; c4 < 8; ++c4) {
                float4 v = make_float4(feat[c4*4+0] * m, feat[c4*4+1] * m,
                                       feat[c4*4+2] * m, feat[c4*4+3] * m);
                *((float4*)(ab + c4 * 4))      = v;   // row 2p
                *((float4*)(ab + 32 + c4 * 4)) = v;   // row 2p+1 (duplicate)
            }
        }
    }
}

extern "C" void kernel_launch(void* const* d_in, const int* in_sizes, int n_in,
                              void* d_out, int out_size, void* d_ws, size_t ws_size,
                              hipStream_t stream) {
    const float* X   = (const float*)d_in[0];
    const float* W1  = (const float*)d_in[1];
    const float* b1  = (const float*)d_in[2];
    const float* W2  = (const float*)d_in[3];
    const float* b2  = (const float*)d_in[4];
    const float* Wp1 = (const float*)d_in[5];
    const float* bp1 = (const float*)d_in[6];
    const float* wp2 = (const float*)d_in[7];
    const float* bp2 = (const float*)d_in[8];
    const float* Wf1 = (const float*)d_in[9];
    const float* bf1 = (const float*)d_in[10];
    const float* Wf2 = (const float*)d_in[11];
    const float* bf2 = (const float*)d_in[12];

    char* ws = (char*)d_ws;
    double* Ap_d  = (double*)(ws + 0);
    double* BpT_d = (double*)(ws + 786432);
    float*  Af_f  = (float*)(ws + 1572864);
    float*  BfT_f = (float*)(ws + 1966080);
    float*  out   = (float*)d_out;

    hipLaunchKernelGGL(k1_encode, dim3(N_NODES), dim3(64), 0, stream,
                       X, W1, b1, W2, b2, Wp1, bp1, Wf1, bf1,
                       Ap_d, BpT_d, Af_f, BfT_f);

    hipLaunchKernelGGL(k2_pairs, dim3(24, 96), dim3(256), 0, stream,
                       Ap_d, BpT_d, Af_f, BfT_f, wp2, bp2, Wf2, bf2, out);
}

// Round 4
// 123.219 us; speedup vs baseline: 2.4706x; 2.4706x over previous
//
#include <hip/hip_runtime.h>
#include <hip/hip_bf16.h>

#define N_NODES 1536
#define PP 1178880LL   // N*(N-1)/2

typedef __attribute__((ext_vector_type(8))) short short8v;  // 8 bf16
typedef __attribute__((ext_vector_type(4))) float f32x4;

// ws layout (bytes):
//   Ap_d : double[N][64]   offset 0        (786432)
//   BpT_d: double[64][N]   offset 786432   (786432)
//   Af_f : float [N][64]   offset 1572864  (393216)  row-major
//   Bf_f : float [N][64]   offset 1966080  (393216)  row-major (changed)

__global__ __launch_bounds__(64) void k1_encode(
    const float* __restrict__ X,  const float* __restrict__ W1, const float* __restrict__ b1,
    const float* __restrict__ W2, const float* __restrict__ b2,
    const float* __restrict__ Wp1, const float* __restrict__ bp1,
    const float* __restrict__ Wf1, const float* __restrict__ bf1,
    double* __restrict__ Ap_d, double* __restrict__ BpT_d,
    float* __restrict__ Af_f, float* __restrict__ Bf_f)
{
    const int i = blockIdx.x;
    const int t = threadIdx.x;
    __shared__ double sh1[64];
    __shared__ double se[64];

    double acc = (double)b1[t];
    const float4* Xv  = (const float4*)(X  + (size_t)i * 128);
    const float4* W1v = (const float4*)(W1 + (size_t)t * 128);
    #pragma unroll
    for (int d = 0; d < 32; ++d) {
        float4 x = Xv[d]; float4 w = W1v[d];
        acc += (double)x.x * (double)w.x + (double)x.y * (double)w.y
             + (double)x.z * (double)w.z + (double)x.w * (double)w.w;
    }
    sh1[t] = acc > 0.0 ? acc : 0.0;
    __syncthreads();

    double e = (double)b2[t];
    const float4* W2v = (const float4*)(W2 + (size_t)t * 64);
    #pragma unroll
    for (int d = 0; d < 16; ++d) {
        float4 w = W2v[d];
        e += sh1[d*4+0] * (double)w.x + sh1[d*4+1] * (double)w.y
           + sh1[d*4+2] * (double)w.z + sh1[d*4+3] * (double)w.w;
    }
    __syncthreads();
    se[t] = e;
    __syncthreads();

    double ap = (double)bp1[t], bp = 0.0, af = (double)bf1[t], bf = 0.0;
    const float4* WpA = (const float4*)(Wp1 + (size_t)t * 128);
    const float4* WpB = (const float4*)(Wp1 + (size_t)t * 128 + 64);
    const float4* WfA = (const float4*)(Wf1 + (size_t)t * 128);
    const float4* WfB = (const float4*)(Wf1 + (size_t)t * 128 + 64);
    #pragma unroll
    for (int d = 0; d < 16; ++d) {
        double e0 = se[d*4+0], e1 = se[d*4+1], e2 = se[d*4+2], e3 = se[d*4+3];
        float4 wa = WpA[d], wb = WpB[d], fa = WfA[d], fb = WfB[d];
        ap += e0*(double)wa.x + e1*(double)wa.y + e2*(double)wa.z + e3*(double)wa.w;
        bp += e0*(double)wb.x + e1*(double)wb.y + e2*(double)wb.z + e3*(double)wb.w;
        af += e0*(double)fa.x + e1*(double)fa.y + e2*(double)fa.z + e3*(double)fa.w;
        bf += e0*(double)fb.x + e1*(double)fb.y + e2*(double)fb.z + e3*(double)fb.w;
    }
    Ap_d[(size_t)i * 64 + t]       = ap;
    BpT_d[(size_t)t * N_NODES + i] = bp;
    Af_f[(size_t)i * 64 + t]       = (float)af;
    Bf_f[(size_t)i * 64 + t]       = (float)bf;
}

__global__ __launch_bounds__(256) void k2_pairs(
    const double* __restrict__ Ap_d, const double* __restrict__ BpT_d,
    const float* __restrict__ Af_f, const float* __restrict__ Bf_f,
    const float* __restrict__ wp2, const float* __restrict__ bp2,
    const float* __restrict__ Wf2, const float* __restrict__ bf2,
    float* __restrict__ out)
{
    const int bj = blockIdx.x, bi = blockIdx.y;
    const int i0 = bi * 16, j0 = bj * 64;
    if (i0 >= j0 + 63) return;

    __shared__ double sBp[64 * 64];   // [k][j]      32 KB
    __shared__ float  sBf[64 * 64];   // [j][k] swz  16 KB
    __shared__ float  sAf[16 * 64];   // [i][k]       4 KB
    const int tid = threadIdx.x;

    #pragma unroll
    for (int a = 0; a < 8; ++a) {
        int F = tid + a * 256;
        int k = F >> 5, q = F & 31;
        ((double2*)sBp)[F] = *((const double2*)(BpT_d + (size_t)k * N_NODES + j0) + q);
    }
    {
        float4* sBf4w = (float4*)sBf;
        const float4* gBf4 = (const float4*)Bf_f;
        #pragma unroll
        for (int a = 0; a < 4; ++a) {
            int F = tid + a * 256;
            int jr = F >> 4, s = F & 15;
            sBf4w[jr * 16 + (s ^ (jr & 7))] = gBf4[(size_t)(j0 + jr) * 16 + s];
        }
        float4* sAf4w = (float4*)sAf;
        const float4* gAf4 = (const float4*)Af_f;
        sAf4w[tid] = gAf4[(size_t)(i0 + (tid >> 4)) * 16 + (tid & 15)];
    }

    const int w = tid >> 6, lane = tid & 63;
    const int lr = lane & 15, hi = lane >> 4;

    // Wf2 bf16 A-fragments [cblk][kblk]: lane -> row c = cb*16+lr, k = kb*32+hi*8+e
    short8v wfrag[2][2];
    #pragma unroll
    for (int cb = 0; cb < 2; ++cb) {
        #pragma unroll
        for (int kb = 0; kb < 2; ++kb) {
            const float* src = Wf2 + (size_t)(cb * 16 + lr) * 64 + kb * 32 + hi * 8;
            short8v f;
            #pragma unroll
            for (int e = 0; e < 8; ++e) {
                __hip_bfloat16 h = __float2bfloat16(src[e]);
                f[e] = *reinterpret_cast<short*>(&h);
            }
            wfrag[cb][kb] = f;
        }
    }
    // bf2 accumulator init: lane's C/D rows c = cb*16 + hi*4 + r
    f32x4 binit[2];
    #pragma unroll
    for (int cb = 0; cb < 2; ++cb) {
        float4 b4 = *(const float4*)(bf2 + cb * 16 + hi * 4);
        f32x4 t; t[0] = b4.x; t[1] = b4.y; t[2] = b4.z; t[3] = b4.w;
        binit[cb] = t;
    }

    __syncthreads();

    const int j = j0 + lane;
    const double bp2v = (double)bp2[0];
    const float4* sBf4 = (const float4*)sBf;
    const float4* sAf4 = (const float4*)sAf;

    for (int ii = 0; ii < 4; ++ii) {
        const int i = i0 + w * 4 + ii;
        if (i >= j0 + 63) break;                 // wave-uniform
        const int il = i - i0;
        const double* aprow = Ap_d + (size_t)i * 64;

        // ---- exact fp64 logit for own column j = j0+lane ----
        double logit = bp2v;
        #pragma unroll
        for (int k = 0; k < 64; ++k) {
            double hb = aprow[k] + sBp[k * 64 + lane];
            hb = hb > 0.0 ? hb : 0.0;
            logit += hb * (double)wp2[k];
        }
        const unsigned long long bal = __ballot(logit > 0.0);

        // ---- feat^T = Wf2 @ g^T via MFMA ----
        float4 afv[2][2];
        #pragma unroll
        for (int kb = 0; kb < 2; ++kb) {
            afv[kb][0] = sAf4[il * 16 + kb * 8 + hi * 2 + 0];
            afv[kb][1] = sAf4[il * 16 + kb * 8 + hi * 2 + 1];
        }
        f32x4 acc[2][4];
        #pragma unroll
        for (int cb = 0; cb < 2; ++cb)
            #pragma unroll
            for (int jb = 0; jb < 4; ++jb)
                acc[cb][jb] = binit[cb];

        #pragma unroll
        for (int jb = 0; jb < 4; ++jb) {
            const int jl = jb * 16 + lr;
            #pragma unroll
            for (int kb = 0; kb < 2; ++kb) {
                float4 b0 = sBf4[jl * 16 + ((kb * 8 + hi * 2 + 0) ^ (jl & 7))];
                float4 b1 = sBf4[jl * 16 + ((kb * 8 + hi * 2 + 1) ^ (jl & 7))];
                float g0 = afv[kb][0].x + b0.x, g1 = afv[kb][0].y + b0.y;
                float g2 = afv[kb][0].z + b0.z, g3 = afv[kb][0].w + b0.w;
                float g4 = afv[kb][1].x + b1.x, g5 = afv[kb][1].y + b1.y;
                float g6 = afv[kb][1].z + b1.z, g7 = afv[kb][1].w + b1.w;
                float gr[8] = {g0, g1, g2, g3, g4, g5, g6, g7};
                short8v gf;
                #pragma unroll
                for (int e = 0; e < 8; ++e) {
                    float r = gr[e] > 0.f ? gr[e] : 0.f;
                    __hip_bfloat16 h = __float2bfloat16(r);
                    gf[e] = *reinterpret_cast<short*>(&h);
                }
                acc[0][jb] = __builtin_amdgcn_mfma_f32_16x16x32_bf16(wfrag[0][kb], gf, acc[0][jb], 0, 0, 0);
                acc[1][jb] = __builtin_amdgcn_mfma_f32_16x16x32_bf16(wfrag[1][kb], gf, acc[1][jb], 0, 0, 0);
            }
        }

        // ---- stores ----
        if (j > i) {
            const float m = ((bal >> lane) & 1ull) ? 1.0f : 0.0f;
            const long long p = (long long)i * (N_NODES - 1)
                              - ((long long)i * (i - 1)) / 2 + (j - i - 1);
            ((float2*)out)[p]            = make_float2((float)i, (float)j);
            ((float2*)(out + 2 * PP))[p] = make_float2((float)j, (float)i);
            ((float2*)(out + 4 * PP))[p] = make_float2(m, m);
        }
        #pragma unroll
        for (int jb = 0; jb < 4; ++jb) {
            const int jf = j0 + jb * 16 + lr;
            if (jf > i) {
                const float mv = ((bal >> (jb * 16 + lr)) & 1ull) ? 1.0f : 0.0f;
                const long long p = (long long)i * (N_NODES - 1)
                                  - ((long long)i * (i - 1)) / 2 + (jf - i - 1);
                float* ab = out + 6 * PP + (p << 6) + hi * 4;
                #pragma unroll
                for (int cb = 0; cb < 2; ++cb) {
                    float4 v = make_float4(acc[cb][jb][0] * mv, acc[cb][jb][1] * mv,
                                           acc[cb][jb][2] * mv, acc[cb][jb][3] * mv);
                    *(float4*)(ab + cb * 16)      = v;   // row 2p
                    *(float4*)(ab + cb * 16 + 32) = v;   // row 2p+1
                }
            }
        }
    }
}

extern "C" void kernel_launch(void* const* d_in, const int* in_sizes, int n_in,
                              void* d_out, int out_size, void* d_ws, size_t ws_size,
                              hipStream_t stream) {
    const float* X   = (const float*)d_in[0];
    const float* W1  = (const float*)d_in[1];
    const float* b1  = (const float*)d_in[2];
    const float* W2  = (const float*)d_in[3];
    const float* b2  = (const float*)d_in[4];
    const float* Wp1 = (const float*)d_in[5];
    const float* bp1 = (const float*)d_in[6];
    const float* wp2 = (const float*)d_in[7];
    const float* bp2 = (const float*)d_in[8];
    const float* Wf1 = (const float*)d_in[9];
    const float* bf1 = (const float*)d_in[10];
    const float* Wf2 = (const float*)d_in[11];
    const float* bf2 = (const float*)d_in[12];

    char* ws = (char*)d_ws;
    double* Ap_d  = (double*)(ws + 0);
    double* BpT_d = (double*)(ws + 786432);
    float*  Af_f  = (float*)(ws + 1572864);
    float*  Bf_f  = (float*)(ws + 1966080);
    float*  out   = (float*)d_out;

    hipLaunchKernelGGL(k1_encode, dim3(N_NODES), dim3(64), 0, stream,
                       X, W1, b1, W2, b2, Wp1, bp1, Wf1, bf1,
                       Ap_d, BpT_d, Af_f, Bf_f);

    hipLaunchKernelGGL(k2_pairs, dim3(24, 96), dim3(256), 0, stream,
                       Ap_d, BpT_d, Af_f, Bf_f, wp2, bp2, Wf2, bf2, out);
}

// Round 5
// 117.809 us; speedup vs baseline: 2.5841x; 1.0459x over previous
//
#include <hip/hip_runtime.h>
#include <hip/hip_bf16.h>

#define N_NODES 1536
#define PP 1178880LL   // N*(N-1)/2

typedef __attribute__((ext_vector_type(8))) short short8v;  // 8 bf16
typedef __attribute__((ext_vector_type(4))) float f32x4;

// ws layout (bytes):
//   Ap_d : double[N][64]   @ 0        (786432)   exact fp64 (fallback)
//   BpT_d: double[64][N]   @ 786432   (786432)   exact fp64 (fallback)
//   Apf  : float [N][64]   @ 1572864  (393216)   fp32 fast path
//   BpTf : float [64][N]   @ 1966080  (393216)   fp32 fast path
//   Af_f : float [N][64]   @ 2359296  (393216)
//   Bf_f : float [N][64]   @ 2752512  (393216)
// total 3145728 bytes

__global__ __launch_bounds__(64) void k1_encode(
    const float* __restrict__ X,  const float* __restrict__ W1, const float* __restrict__ b1,
    const float* __restrict__ W2, const float* __restrict__ b2,
    const float* __restrict__ Wp1, const float* __restrict__ bp1,
    const float* __restrict__ Wf1, const float* __restrict__ bf1,
    double* __restrict__ Ap_d, double* __restrict__ BpT_d,
    float* __restrict__ Apf, float* __restrict__ BpTf,
    float* __restrict__ Af_f, float* __restrict__ Bf_f)
{
    const int i = blockIdx.x;
    const int t = threadIdx.x;
    __shared__ double sh1[64];
    __shared__ double se[64];

    double acc = (double)b1[t];
    const float4* Xv  = (const float4*)(X  + (size_t)i * 128);
    const float4* W1v = (const float4*)(W1 + (size_t)t * 128);
    #pragma unroll
    for (int d = 0; d < 32; ++d) {
        float4 x = Xv[d]; float4 w = W1v[d];
        acc += (double)x.x * (double)w.x + (double)x.y * (double)w.y
             + (double)x.z * (double)w.z + (double)x.w * (double)w.w;
    }
    sh1[t] = acc > 0.0 ? acc : 0.0;
    __syncthreads();

    double e = (double)b2[t];
    const float4* W2v = (const float4*)(W2 + (size_t)t * 64);
    #pragma unroll
    for (int d = 0; d < 16; ++d) {
        float4 w = W2v[d];
        e += sh1[d*4+0] * (double)w.x + sh1[d*4+1] * (double)w.y
           + sh1[d*4+2] * (double)w.z + sh1[d*4+3] * (double)w.w;
    }
    __syncthreads();
    se[t] = e;
    __syncthreads();

    double ap = (double)bp1[t], bp = 0.0, af = (double)bf1[t], bf = 0.0;
    const float4* WpA = (const float4*)(Wp1 + (size_t)t * 128);
    const float4* WpB = (const float4*)(Wp1 + (size_t)t * 128 + 64);
    const float4* WfA = (const float4*)(Wf1 + (size_t)t * 128);
    const float4* WfB = (const float4*)(Wf1 + (size_t)t * 128 + 64);
    #pragma unroll
    for (int d = 0; d < 16; ++d) {
        double e0 = se[d*4+0], e1 = se[d*4+1], e2 = se[d*4+2], e3 = se[d*4+3];
        float4 wa = WpA[d], wb = WpB[d], fa = WfA[d], fb = WfB[d];
        ap += e0*(double)wa.x + e1*(double)wa.y + e2*(double)wa.z + e3*(double)wa.w;
        bp += e0*(double)wb.x + e1*(double)wb.y + e2*(double)wb.z + e3*(double)wb.w;
        af += e0*(double)fa.x + e1*(double)fa.y + e2*(double)fa.z + e3*(double)fa.w;
        bf += e0*(double)fb.x + e1*(double)fb.y + e2*(double)fb.z + e3*(double)fb.w;
    }
    Ap_d[(size_t)i * 64 + t]       = ap;
    BpT_d[(size_t)t * N_NODES + i] = bp;
    Apf[(size_t)i * 64 + t]        = (float)ap;
    BpTf[(size_t)t * N_NODES + i]  = (float)bp;
    Af_f[(size_t)i * 64 + t]       = (float)af;
    Bf_f[(size_t)i * 64 + t]       = (float)bf;
}

__global__ __launch_bounds__(256) void k2_pairs(
    const double* __restrict__ Ap_d, const double* __restrict__ BpT_d,
    const float* __restrict__ Apf, const float* __restrict__ BpTf,
    const float* __restrict__ Af_f, const float* __restrict__ Bf_f,
    const float* __restrict__ wp2, const float* __restrict__ bp2,
    const float* __restrict__ Wf2, const float* __restrict__ bf2,
    float* __restrict__ out)
{
    const int bj = blockIdx.x, bi = blockIdx.y;
    const int i0 = bi * 16, j0 = bj * 64;
    if (i0 >= j0 + 63) return;

    __shared__ float sBp[64 * 64];   // [k][j] f32  16 KB
    __shared__ float sBf[64 * 64];   // [j][k] swz  16 KB
    __shared__ float sAf[16 * 64];   // [i][k]       4 KB
    const int tid = threadIdx.x;

    {
        float4* sBp4w = (float4*)sBp;
        const float4* gBp4 = (const float4*)BpTf;
        #pragma unroll
        for (int a = 0; a < 4; ++a) {
            int F = tid + a * 256;              // float4 idx 0..1023
            int k = F >> 4, q = F & 15;
            sBp4w[F] = gBp4[(size_t)k * (N_NODES / 4) + (j0 >> 2) + q];
        }
        float4* sBf4w = (float4*)sBf;
        const float4* gBf4 = (const float4*)Bf_f;
        #pragma unroll
        for (int a = 0; a < 4; ++a) {
            int F = tid + a * 256;
            int jr = F >> 4, s = F & 15;
            sBf4w[jr * 16 + (s ^ (jr & 7))] = gBf4[(size_t)(j0 + jr) * 16 + s];
        }
        float4* sAf4w = (float4*)sAf;
        const float4* gAf4 = (const float4*)Af_f;
        sAf4w[tid] = gAf4[(size_t)(i0 + (tid >> 4)) * 16 + (tid & 15)];
    }

    const int w = tid >> 6, lane = tid & 63;
    const int lr = lane & 15, hi = lane >> 4;

    // Wf2 bf16 A-fragments [cblk][kblk]: lane -> row c = cb*16+lr, k = kb*32+hi*8+e
    short8v wfrag[2][2];
    #pragma unroll
    for (int cb = 0; cb < 2; ++cb) {
        #pragma unroll
        for (int kb = 0; kb < 2; ++kb) {
            const float* src = Wf2 + (size_t)(cb * 16 + lr) * 64 + kb * 32 + hi * 8;
            short8v f;
            #pragma unroll
            for (int e = 0; e < 8; ++e) {
                __hip_bfloat16 h = __float2bfloat16(src[e]);
                f[e] = *reinterpret_cast<short*>(&h);
            }
            wfrag[cb][kb] = f;
        }
    }
    f32x4 binit[2];
    #pragma unroll
    for (int cb = 0; cb < 2; ++cb) {
        float4 b4 = *(const float4*)(bf2 + cb * 16 + hi * 4);
        f32x4 t; t[0] = b4.x; t[1] = b4.y; t[2] = b4.z; t[3] = b4.w;
        binit[cb] = t;
    }

    __syncthreads();

    const int j = j0 + lane;
    const float  bp2f = bp2[0];
    const double bp2v = (double)bp2[0];
    const float4* sBf4 = (const float4*)sBf;
    const float4* sAf4 = (const float4*)sAf;

    for (int ii = 0; ii < 4; ++ii) {
        const int i = i0 + w * 4 + ii;
        if (i >= j0 + 63) break;                 // wave-uniform
        const int il = i - i0;

        // ---- fp32 logit fast path (exact-sign fallback below) ----
        const float* aprowf = Apf + (size_t)i * 64;
        float logf = bp2f;
        #pragma unroll
        for (int k = 0; k < 64; ++k) {
            float hb = aprowf[k] + sBp[k * 64 + lane];
            hb = hb > 0.f ? hb : 0.f;
            logf = fmaf(hb, wp2[k], logf);
        }
        bool maskb = logf > 0.f;
        if (__any(fabsf(logf) < 1e-4f)) {        // rare: decide exactly in fp64
            const double* aprow = Ap_d + (size_t)i * 64;
            double logit = bp2v;
            for (int k = 0; k < 64; ++k) {
                double hb = aprow[k] + BpT_d[(size_t)k * N_NODES + j];
                hb = hb > 0.0 ? hb : 0.0;
                logit = fma(hb, (double)wp2[k], logit);
            }
            maskb = logit > 0.0;
        }
        const unsigned long long bal = __ballot(maskb);

        // ---- feat^T = Wf2 @ g^T via MFMA ----
        float4 afv[2][2];
        #pragma unroll
        for (int kb = 0; kb < 2; ++kb) {
            afv[kb][0] = sAf4[il * 16 + kb * 8 + hi * 2 + 0];
            afv[kb][1] = sAf4[il * 16 + kb * 8 + hi * 2 + 1];
        }
        f32x4 acc[2][4];
        #pragma unroll
        for (int cb = 0; cb < 2; ++cb)
            #pragma unroll
            for (int jb = 0; jb < 4; ++jb)
                acc[cb][jb] = binit[cb];

        #pragma unroll
        for (int jb = 0; jb < 4; ++jb) {
            const int jl = jb * 16 + lr;
            #pragma unroll
            for (int kb = 0; kb < 2; ++kb) {
                float4 b0 = sBf4[jl * 16 + ((kb * 8 + hi * 2 + 0) ^ (jl & 7))];
                float4 b1 = sBf4[jl * 16 + ((kb * 8 + hi * 2 + 1) ^ (jl & 7))];
                float g0 = afv[kb][0].x + b0.x, g1 = afv[kb][0].y + b0.y;
                float g2 = afv[kb][0].z + b0.z, g3 = afv[kb][0].w + b0.w;
                float g4 = afv[kb][1].x + b1.x, g5 = afv[kb][1].y + b1.y;
                float g6 = afv[kb][1].z + b1.z, g7 = afv[kb][1].w + b1.w;
                float gr[8] = {g0, g1, g2, g3, g4, g5, g6, g7};
                short8v gf;
                #pragma unroll
                for (int e = 0; e < 8; ++e) {
                    float r = gr[e] > 0.f ? gr[e] : 0.f;
                    __hip_bfloat16 h = __float2bfloat16(r);
                    gf[e] = *reinterpret_cast<short*>(&h);
                }
                acc[0][jb] = __builtin_amdgcn_mfma_f32_16x16x32_bf16(wfrag[0][kb], gf, acc[0][jb], 0, 0, 0);
                acc[1][jb] = __builtin_amdgcn_mfma_f32_16x16x32_bf16(wfrag[1][kb], gf, acc[1][jb], 0, 0, 0);
            }
        }

        // ---- stores ----
        if (j > i) {
            const float m = ((bal >> lane) & 1ull) ? 1.0f : 0.0f;
            const long long p = (long long)i * (N_NODES - 1)
                              - ((long long)i * (i - 1)) / 2 + (j - i - 1);
            ((float2*)out)[p]            = make_float2((float)i, (float)j);
            ((float2*)(out + 2 * PP))[p] = make_float2((float)j, (float)i);
            ((float2*)(out + 4 * PP))[p] = make_float2(m, m);
        }
        #pragma unroll
        for (int jb = 0; jb < 4; ++jb) {
            const int jf = j0 + jb * 16 + lr;
            if (jf > i) {
                const float mv = ((bal >> (jb * 16 + lr)) & 1ull) ? 1.0f : 0.0f;
                const long long p = (long long)i * (N_NODES - 1)
                                  - ((long long)i * (i - 1)) / 2 + (jf - i - 1);
                float* ab = out + 6 * PP + (p << 6) + hi * 4;
                #pragma unroll
                for (int cb = 0; cb < 2; ++cb) {
                    float4 v = make_float4(acc[cb][jb][0] * mv, acc[cb][jb][1] * mv,
                                           acc[cb][jb][2] * mv, acc[cb][jb][3] * mv);
                    *(float4*)(ab + cb * 16)      = v;   // row 2p
                    *(float4*)(ab + cb * 16 + 32) = v;   // row 2p+1
                }
            }
        }
    }
}

extern "C" void kernel_launch(void* const* d_in, const int* in_sizes, int n_in,
                              void* d_out, int out_size, void* d_ws, size_t ws_size,
                              hipStream_t stream) {
    const float* X   = (const float*)d_in[0];
    const float* W1  = (const float*)d_in[1];
    const float* b1  = (const float*)d_in[2];
    const float* W2  = (const float*)d_in[3];
    const float* b2  = (const float*)d_in[4];
    const float* Wp1 = (const float*)d_in[5];
    const float* bp1 = (const float*)d_in[6];
    const float* wp2 = (const float*)d_in[7];
    const float* bp2 = (const float*)d_in[8];
    const float* Wf1 = (const float*)d_in[9];
    const float* bf1 = (const float*)d_in[10];
    const float* Wf2 = (const float*)d_in[11];
    const float* bf2 = (const float*)d_in[12];

    char* ws = (char*)d_ws;
    double* Ap_d  = (double*)(ws + 0);
    double* BpT_d = (double*)(ws + 786432);
    float*  Apf   = (float*)(ws + 1572864);
    float*  BpTf  = (float*)(ws + 1966080);
    float*  Af_f  = (float*)(ws + 2359296);
    float*  Bf_f  = (float*)(ws + 2752512);
    float*  out   = (float*)d_out;

    hipLaunchKernelGGL(k1_encode, dim3(N_NODES), dim3(64), 0, stream,
                       X, W1, b1, W2, b2, Wp1, bp1, Wf1, bf1,
                       Ap_d, BpT_d, Apf, BpTf, Af_f, Bf_f);

    hipLaunchKernelGGL(k2_pairs, dim3(24, 96), dim3(256), 0, stream,
                       Ap_d, BpT_d, Apf, BpTf, Af_f, Bf_f, wp2, bp2, Wf2, bf2, out);
}